// Round 5
// baseline (376.420 us; speedup 1.0000x reference)
//
#include <hip/hip_runtime.h>

typedef unsigned short u16;
typedef __bf16 bf16x8 __attribute__((ext_vector_type(8)));
typedef float f32x4 __attribute__((ext_vector_type(4)));

#define MFMA16(a,b,c) __builtin_amdgcn_mfma_f32_16x16x32_bf16((a),(b),(c),0,0,0)

__device__ __forceinline__ float bfu2f(u16 u){ union{unsigned x; float f;} c; c.x=((unsigned)u)<<16; return c.f; }
__device__ __forceinline__ u16 f2bfu(float f){ union{float f; unsigned x;} c; c.f=f; unsigned r=c.x+0x7fffu+((c.x>>16)&1u); return (u16)(r>>16); }
__device__ __forceinline__ bf16x8 ldb8(const void* p){ union{uint4 u; bf16x8 b;} c; c.u=*(const uint4*)p; return c.b; }

// ---- workspace layout (bytes) ----  (emb2 f32 lives in d_out, NOT here)
#define WS_WQKVT  ((size_t)0)        // bf16 [384][128]  (q rows pre-scaled by 1/sqrt(32))
#define WS_WOT    ((size_t)98304)    // bf16 [128][128]
#define WS_WPT    ((size_t)131072)   // bf16 [128][128]
#define WS_W1HI   ((size_t)163840)   // bf16 [512][128]  w1^T split-high
#define WS_W1LO   ((size_t)294912)   // bf16 [512][128]  w1^T split-low
#define WS_W2HI   ((size_t)425984)   // bf16 [128][512]  w2^T split-high
#define WS_W2LO   ((size_t)557056)   // bf16 [128][512]  w2^T split-low
#define WS_BQKV   ((size_t)688128)   // f32  [384]
#define WS_BM     ((size_t)689664)   // f32  [4][4][64][64] bias+mask
// total 951808 bytes

// ================= prep: weight transposes (f32 -> bf16 / split) + bias/mask =================
__global__ void k_prep(const float* __restrict__ wq, const float* __restrict__ bq,
                       const float* __restrict__ wk, const float* __restrict__ bk,
                       const float* __restrict__ wv, const float* __restrict__ bv,
                       const float* __restrict__ bt,
                       const float* __restrict__ wo, const float* __restrict__ wp,
                       const float* __restrict__ w1, const float* __restrict__ w2,
                       u16* __restrict__ wqkvT, float* __restrict__ bqkv,
                       u16* __restrict__ woT, u16* __restrict__ wpT,
                       u16* __restrict__ w1hi, u16* __restrict__ w1lo,
                       u16* __restrict__ w2hi, u16* __restrict__ w2lo,
                       float* __restrict__ biasmask)
{
  int i = blockIdx.x*256 + threadIdx.x;
  const float qsc = 0.17677669529663687f; // 1/sqrt(32)
  if (i < 49152) {                       // wqkvT[j][c] = W[c][j]  (j<128:q,<256:k,<384:v)
    int j = i >> 7, c = i & 127, m = j >> 7, jj = j & 127;
    float f = (m==0?wq:(m==1?wk:wv))[c*128 + jj]; if (m==0) f *= qsc;
    wqkvT[i] = f2bfu(f); return;
  }
  i -= 49152;
  if (i < 384) { int m=i>>7, jj=i&127; float f=(m==0?bq:(m==1?bk:bv))[jj]; if(m==0) f*=qsc; bqkv[i]=f; return; }
  i -= 384;
  if (i < 16384) { int c=i>>7, j=i&127; woT[i] = f2bfu(wo[j*128 + c]); return; }   // woT[c][j=h*32+d]
  i -= 16384;
  if (i < 16384) { int c=i>>7, j=i&127; wpT[i] = f2bfu(wp[j*128 + c]); return; }   // wpT[c][j] = wp[j][c]
  i -= 16384;
  if (i < 65536) {                      // w1T split: [j][c] = w1[c][j]
    int j=i>>7, c=i&127; float f = w1[c*512 + j];
    u16 h = f2bfu(f); w1hi[i] = h; w1lo[i] = f2bfu(f - bfu2f(h)); return;
  }
  i -= 65536;
  if (i < 65536) {                      // w2T split: [c][k] = w2[k][c]
    int c=i>>9, k=i&511; float f = w2[k*128 + c];
    u16 h = f2bfu(f); w2hi[i] = h; w2lo[i] = f2bfu(f - bfu2f(h)); return;
  }
  i -= 65536;
  if (i < 65536) {
    int var=i>>14, h=(i>>12)&3, q=(i>>6)&63, k=i&63;
    int qr=q>>3, qc=q&7, kr=k>>3, kc=k&7;
    int vr=var>>1, vc=var&1;
    // shift-mask: sm(r,c)=6*(r>=4)+2*(c>=4); variety only in window-row 0 / window-col 0
    bool ok = ((vr==0) || ((qr>=4)==(kr>=4))) && ((vc==0) || ((qc>=4)==(kc>=4)));
    biasmask[i] = ok ? bt[h*225 + (qr-kr+7)*15 + (qc-kc+7)] : -1e30f;
  }
}

// ================= attention kernel: one block per (b, wrow, wcol) window =================
#define XB_OFF 0        // 64 x 256B rows, swizzled  (x after LN; later attn-out)
#define VT_OFF 16384    // vT[4][32][72] bf16
#define QS_OFF 34816    // qs[4][64][40] bf16 ; later P[4][64][72] ; later proj1 [64][256B]
#define KS_OFF 55296    // ks[4][64][40] bf16
#define SMEM_BYTES 75776

__global__ __launch_bounds__(256, 2) void k_attn(
    const float* __restrict__ emb, const float* __restrict__ g1, const float* __restrict__ be1,
    const u16* __restrict__ wqkvT, const float* __restrict__ bqkv,
    const float* __restrict__ biasmask,
    const u16* __restrict__ woT, const float* __restrict__ bo,
    const u16* __restrict__ wpT, const float* __restrict__ bp,
    float* __restrict__ emb2)
{
  __shared__ __attribute__((aligned(16))) char smem[SMEM_BYTES];
  const int bx = blockIdx.x;
  const int bb  = bx / 49;
  const int wri = (bx % 49) / 7;
  const int wci = bx % 7;
  const int tid  = threadIdx.x;
  const int lane = tid & 63, wid = tid >> 6;
  const int lc = lane & 15, lh = lane >> 4;

  // ---- LN1 + shifted-window gather -> xb (swizzled bf16 [64][128]) ----
  {
    const int t = tid >> 2, p = tid & 3;
    const int sr = t >> 3, sc = t & 7;
    const int rs = (wri*8 + sr + 52) % 56;
    const int cs = (wci*8 + sc + 52) % 56;
    const float* src = emb + (((bb*56 + rs)*56 + cs) << 7) + (p << 5);
    float xv[32]; float s1 = 0.f, s2 = 0.f;
    #pragma unroll
    for (int q4 = 0; q4 < 8; ++q4) {
      float4 raw = *(const float4*)(src + q4*4);
      const float* r4 = (const float*)&raw;
      #pragma unroll
      for (int j = 0; j < 4; ++j) { float f = r4[j]; xv[q4*4+j] = f; s1 += f; s2 += f*f; }
    }
    s1 += __shfl_xor(s1,1); s1 += __shfl_xor(s1,2);
    s2 += __shfl_xor(s2,1); s2 += __shfl_xor(s2,2);
    const float mu   = s1 * 0.0078125f;
    const float rstd = rsqrtf(s2*0.0078125f - mu*mu + 1e-6f);
    unsigned ow[16];
    #pragma unroll
    for (int q4 = 0; q4 < 8; ++q4) {
      float4 gs  = *(const float4*)(g1  + (p<<5) + q4*4);
      float4 gbv = *(const float4*)(be1 + (p<<5) + q4*4);
      const float* s4 = (const float*)&gs; const float* b4 = (const float*)&gbv;
      #pragma unroll
      for (int j2 = 0; j2 < 2; ++j2) {
        float a0 = (xv[q4*4+j2*2]   - mu)*rstd*s4[j2*2]   + b4[j2*2];
        float a1 = (xv[q4*4+j2*2+1] - mu)*rstd*s4[j2*2+1] + b4[j2*2+1];
        ow[q4*2+j2] = ((unsigned)f2bfu(a1)<<16) | (unsigned)f2bfu(a0);
      }
    }
    #pragma unroll
    for (int s = 0; s < 4; ++s) {
      const int cb = (p<<6) + s*16;
      *(uint4*)(smem + ((t<<8) + (cb ^ ((t&7)<<4)))) = *(const uint4*)(ow + s*4);
    }
  }
  __syncthreads();

  // ---- QKV GEMM: (64x128) @ (128x384), bias pre-loaded into accumulators ----
  {
    f32x4 acc[4][6];
    #pragma unroll
    for (int nt = 0; nt < 6; ++nt) {
      const float bj = bqkv[wid*96 + nt*16 + lc];
      #pragma unroll
      for (int mt = 0; mt < 4; ++mt) acc[mt][nt] = (f32x4){bj,bj,bj,bj};
    }
    #pragma unroll
    for (int kk = 0; kk < 4; ++kk) {
      bf16x8 a[4];
      #pragma unroll
      for (int mt = 0; mt < 4; ++mt) {
        const int row = mt*16 + lc, cb = kk*64 + lh*16;
        a[mt] = ldb8(smem + ((row<<8) + (cb ^ ((row&7)<<4))));
      }
      #pragma unroll
      for (int nt = 0; nt < 6; ++nt) {
        const int j = wid*96 + nt*16 + lc;
        const bf16x8 bfr = ldb8(wqkvT + j*128 + kk*32 + lh*8);
        #pragma unroll
        for (int mt = 0; mt < 4; ++mt) acc[mt][nt] = MFMA16(a[mt], bfr, acc[mt][nt]);
      }
    }
    // scatter to qs/ks/vT (branch uniform per (wid,nt) tile)
    #pragma unroll
    for (int nt = 0; nt < 6; ++nt) {
      const int j = wid*96 + nt*16 + lc;
      const int m = j >> 7, jj = j & 127, hh = jj >> 5, dd = jj & 31;
      #pragma unroll
      for (int mt = 0; mt < 4; ++mt)
        #pragma unroll
        for (int r = 0; r < 4; ++r) {
          const int row = mt*16 + lh*4 + r;
          const u16 hv = f2bfu(acc[mt][nt][r]);
          if (m == 0)      *(u16*)(smem + QS_OFF + (((hh*64+row)*40 + dd)<<1)) = hv;
          else if (m == 1) *(u16*)(smem + KS_OFF + (((hh*64+row)*40 + dd)<<1)) = hv;
          else             *(u16*)(smem + VT_OFF + (((hh*32+dd)*72 + row)<<1)) = hv;
        }
    }
  }
  __syncthreads();

  // ---- per-head attention: wave = head ----
  f32x4 o[4][2];
  {
    const int h = wid;
    const int varid = ((wri==0)?2:0) | ((wci==0)?1:0);
    const float* bm = biasmask + ((size_t)(varid*4 + h) << 12);
    f32x4 lg[4][4];
    #pragma unroll
    for (int mt = 0; mt < 4; ++mt)
      #pragma unroll
      for (int nt = 0; nt < 4; ++nt)
        #pragma unroll
        for (int r = 0; r < 4; ++r)
          lg[mt][nt][r] = bm[(mt*16 + lh*4 + r)*64 + nt*16 + lc];
    {
      bf16x8 aq[4];
      #pragma unroll
      for (int mt = 0; mt < 4; ++mt)
        aq[mt] = ldb8(smem + QS_OFF + (((h*64 + mt*16 + lc)*40 + lh*8)<<1));
      #pragma unroll
      for (int nt = 0; nt < 4; ++nt) {
        const bf16x8 bk8 = ldb8(smem + KS_OFF + (((h*64 + nt*16 + lc)*40 + lh*8)<<1));
        #pragma unroll
        for (int mt = 0; mt < 4; ++mt) lg[mt][nt] = MFMA16(aq[mt], bk8, lg[mt][nt]);
      }
    }
    // wave-parallel softmax over 64 cols (16-lane shfl groups, 4 vals/lane)
    #pragma unroll
    for (int mt = 0; mt < 4; ++mt)
      #pragma unroll
      for (int r = 0; r < 4; ++r) {
        float m0 = fmaxf(fmaxf(lg[mt][0][r], lg[mt][1][r]), fmaxf(lg[mt][2][r], lg[mt][3][r]));
        m0 = fmaxf(m0, __shfl_xor(m0,1)); m0 = fmaxf(m0, __shfl_xor(m0,2));
        m0 = fmaxf(m0, __shfl_xor(m0,4)); m0 = fmaxf(m0, __shfl_xor(m0,8));
        float ss = 0.f;
        #pragma unroll
        for (int nt = 0; nt < 4; ++nt) { const float pz = __expf(lg[mt][nt][r]-m0); lg[mt][nt][r]=pz; ss += pz; }
        ss += __shfl_xor(ss,1); ss += __shfl_xor(ss,2); ss += __shfl_xor(ss,4); ss += __shfl_xor(ss,8);
        const float inv = 1.f / ss;
        #pragma unroll
        for (int nt = 0; nt < 4; ++nt) lg[mt][nt][r] *= inv;
      }
    __syncthreads();   // all waves done reading qs/ks before P overwrites that region
    #pragma unroll
    for (int mt = 0; mt < 4; ++mt)
      #pragma unroll
      for (int nt = 0; nt < 4; ++nt)
        #pragma unroll
        for (int r = 0; r < 4; ++r)
          *(u16*)(smem + QS_OFF + (((h*64 + mt*16 + lh*4 + r)*72 + nt*16 + lc)<<1)) = f2bfu(lg[mt][nt][r]);
    // PV: (64x64) @ (64x32)
    #pragma unroll
    for (int mt = 0; mt < 4; ++mt) { o[mt][0] = (f32x4){0.f,0.f,0.f,0.f}; o[mt][1] = (f32x4){0.f,0.f,0.f,0.f}; }
    #pragma unroll
    for (int kk = 0; kk < 2; ++kk) {
      bf16x8 ap[4];
      #pragma unroll
      for (int mt = 0; mt < 4; ++mt)
        ap[mt] = ldb8(smem + QS_OFF + (((h*64 + mt*16 + lc)*72 + kk*32 + lh*8)<<1));
      #pragma unroll
      for (int nt = 0; nt < 2; ++nt) {
        const bf16x8 bv8 = ldb8(smem + VT_OFF + (((h*32 + nt*16 + lc)*72 + kk*32 + lh*8)<<1));
        #pragma unroll
        for (int mt = 0; mt < 4; ++mt) o[mt][nt] = MFMA16(ap[mt], bv8, o[mt][nt]);
      }
    }
    // attn-out -> xb (reuse, swizzled), col = h*32 + ...
    #pragma unroll
    for (int mt = 0; mt < 4; ++mt)
      #pragma unroll
      for (int nt = 0; nt < 2; ++nt)
        #pragma unroll
        for (int r = 0; r < 4; ++r) {
          const int row = mt*16 + lh*4 + r;
          const int cbyte = (h*32 + nt*16 + lc) << 1;
          *(u16*)(smem + ((row<<8) + (cbyte ^ ((row&7)<<4)))) = f2bfu(o[mt][nt][r]);
        }
  }
  __syncthreads();

  // ---- wo GEMM: (64x128) @ (128x128) -> proj1 (QS region, swizzled) ----
  {
    f32x4 p1[4][2];
    #pragma unroll
    for (int nt = 0; nt < 2; ++nt) {
      const float bc = bo[wid*32 + nt*16 + lc];
      #pragma unroll
      for (int mt = 0; mt < 4; ++mt) p1[mt][nt] = (f32x4){bc,bc,bc,bc};
    }
    #pragma unroll
    for (int kk = 0; kk < 4; ++kk) {
      bf16x8 a[4];
      #pragma unroll
      for (int mt = 0; mt < 4; ++mt) {
        const int row = mt*16 + lc, cb = kk*64 + lh*16;
        a[mt] = ldb8(smem + ((row<<8) + (cb ^ ((row&7)<<4))));
      }
      #pragma unroll
      for (int nt = 0; nt < 2; ++nt) {
        const int c = wid*32 + nt*16 + lc;
        const bf16x8 b8 = ldb8(woT + c*128 + kk*32 + lh*8);
        #pragma unroll
        for (int mt = 0; mt < 4; ++mt) p1[mt][nt] = MFMA16(a[mt], b8, p1[mt][nt]);
      }
    }
    #pragma unroll
    for (int mt = 0; mt < 4; ++mt)
      #pragma unroll
      for (int nt = 0; nt < 2; ++nt)
        #pragma unroll
        for (int r = 0; r < 4; ++r) {
          const int row = mt*16 + lh*4 + r;
          const int cbyte = (wid*32 + nt*16 + lc) << 1;
          *(u16*)(smem + QS_OFF + ((row<<8) + (cbyte ^ ((row&7)<<4)))) = f2bfu(p1[mt][nt][r]);
        }
  }
  __syncthreads();

  // ---- wp GEMM + residual -> emb2 f32 (un-rolled coords) ----
  {
    f32x4 p2[4][2];
    #pragma unroll
    for (int nt = 0; nt < 2; ++nt) {
      const float bc = bp[wid*32 + nt*16 + lc];
      #pragma unroll
      for (int mt = 0; mt < 4; ++mt) p2[mt][nt] = (f32x4){bc,bc,bc,bc};
    }
    #pragma unroll
    for (int kk = 0; kk < 4; ++kk) {
      bf16x8 a[4];
      #pragma unroll
      for (int mt = 0; mt < 4; ++mt) {
        const int row = mt*16 + lc, cb = kk*64 + lh*16;
        a[mt] = ldb8(smem + QS_OFF + ((row<<8) + (cb ^ ((row&7)<<4))));
      }
      #pragma unroll
      for (int nt = 0; nt < 2; ++nt) {
        const int c = wid*32 + nt*16 + lc;
        const bf16x8 b8 = ldb8(wpT + c*128 + kk*32 + lh*8);
        #pragma unroll
        for (int mt = 0; mt < 4; ++mt) p2[mt][nt] = MFMA16(a[mt], b8, p2[mt][nt]);
      }
    }
    #pragma unroll
    for (int mt = 0; mt < 4; ++mt)
      #pragma unroll
      for (int nt = 0; nt < 2; ++nt) {
        const int c = wid*32 + nt*16 + lc;
        #pragma unroll
        for (int r = 0; r < 4; ++r) {
          const int row = mt*16 + lh*4 + r;
          const int sr = row >> 3, sc = row & 7;
          const int rs = (wri*8 + sr + 52) % 56;
          const int cs = (wci*8 + sc + 52) % 56;
          const int gi = (((bb*56 + rs)*56 + cs) << 7) + c;
          emb2[gi] = emb[gi] + p2[mt][nt][r];
        }
      }
  }
}

// ================= MLP kernel: LN2 + gelu MLP (double-bf16 split GEMMs) =================
// emb2 aliases outp (d_out). Safe: each block reads only its 64 tokens before its
// first __syncthreads() and writes the same 64 tokens only at the very end.
#define X2HI 0
#define X2LO 16384
#define HHI  32768
#define HLO  49152
// 65536 bytes LDS

__global__ __launch_bounds__(256, 2) void k_mlp(
    const float* __restrict__ emb2, const float* __restrict__ g2, const float* __restrict__ be2,
    const u16* __restrict__ w1hi, const u16* __restrict__ w1lo, const float* __restrict__ b1,
    const u16* __restrict__ w2hi, const u16* __restrict__ w2lo, const float* __restrict__ b2,
    float* __restrict__ outp)
{
  __shared__ __attribute__((aligned(16))) char sm2[65536];
  const int tid = threadIdx.x;
  const int lane = tid & 63, wid = tid >> 6;
  const int lc = lane & 15, lh = lane >> 4;
  const int tk0 = blockIdx.x << 6;

  { // LN2 -> x2 split (hi/lo swizzled bf16 [64][128])
    const int t = tid >> 2, p = tid & 3;
    const float* src = emb2 + ((size_t)(tk0 + t) << 7) + (p << 5);
    float xv[32]; float s1 = 0.f, s2 = 0.f;
    #pragma unroll
    for (int q4 = 0; q4 < 8; ++q4) {
      float4 raw = *(const float4*)(src + q4*4);
      const float* r4 = (const float*)&raw;
      #pragma unroll
      for (int j = 0; j < 4; ++j) { float f = r4[j]; xv[q4*4+j] = f; s1 += f; s2 += f*f; }
    }
    s1 += __shfl_xor(s1,1); s1 += __shfl_xor(s1,2);
    s2 += __shfl_xor(s2,1); s2 += __shfl_xor(s2,2);
    const float mu   = s1 * 0.0078125f;
    const float rstd = rsqrtf(s2*0.0078125f - mu*mu + 1e-6f);
    unsigned owh[16], owl[16];
    #pragma unroll
    for (int q4 = 0; q4 < 8; ++q4) {
      float4 gs  = *(const float4*)(g2  + (p<<5) + q4*4);
      float4 gbv = *(const float4*)(be2 + (p<<5) + q4*4);
      const float* s4 = (const float*)&gs; const float* b4 = (const float*)&gbv;
      #pragma unroll
      for (int j2 = 0; j2 < 2; ++j2) {
        float a0 = (xv[q4*4+j2*2]   - mu)*rstd*s4[j2*2]   + b4[j2*2];
        float a1 = (xv[q4*4+j2*2+1] - mu)*rstd*s4[j2*2+1] + b4[j2*2+1];
        u16 h0 = f2bfu(a0), h1 = f2bfu(a1);
        u16 l0 = f2bfu(a0 - bfu2f(h0)), l1 = f2bfu(a1 - bfu2f(h1));
        owh[q4*2+j2] = ((unsigned)h1<<16) | (unsigned)h0;
        owl[q4*2+j2] = ((unsigned)l1<<16) | (unsigned)l0;
      }
    }
    #pragma unroll
    for (int s = 0; s < 4; ++s) {
      const int cb = (p<<6) + s*16;
      const int adr = (t<<8) + (cb ^ ((t&7)<<4));
      *(uint4*)(sm2 + X2HI + adr) = *(const uint4*)(owh + s*4);
      *(uint4*)(sm2 + X2LO + adr) = *(const uint4*)(owl + s*4);
    }
  }
  __syncthreads();

  // GEMM2 accumulators (full output, accumulated over 4 j-quarters)
  f32x4 acc2[4][2];
  #pragma unroll
  for (int nt = 0; nt < 2; ++nt) {
    const float bc = b2[wid*32 + nt*16 + lc];
    #pragma unroll
    for (int mt = 0; mt < 4; ++mt) acc2[mt][nt] = (f32x4){bc,bc,bc,bc};
  }

  for (int jq = 0; jq < 4; ++jq) {
    { // GEMM1 quarter: (64x128)@(128x128) split -> gelu -> h hi/lo
      f32x4 acc1[4][2];
      #pragma unroll
      for (int nt = 0; nt < 2; ++nt) {
        const float bj = b1[jq*128 + wid*32 + nt*16 + lc];
        #pragma unroll
        for (int mt = 0; mt < 4; ++mt) acc1[mt][nt] = (f32x4){bj,bj,bj,bj};
      }
      #pragma unroll
      for (int kk = 0; kk < 4; ++kk) {
        bf16x8 ahi[4], alo[4];
        #pragma unroll
        for (int mt = 0; mt < 4; ++mt) {
          const int row = mt*16 + lc, cb = kk*64 + lh*16;
          const int adr = (row<<8) + (cb ^ ((row&7)<<4));
          ahi[mt] = ldb8(sm2 + X2HI + adr);
          alo[mt] = ldb8(sm2 + X2LO + adr);
        }
        #pragma unroll
        for (int nt = 0; nt < 2; ++nt) {
          const int j = jq*128 + wid*32 + nt*16 + lc;
          const bf16x8 bhi = ldb8(w1hi + j*128 + kk*32 + lh*8);
          const bf16x8 blo = ldb8(w1lo + j*128 + kk*32 + lh*8);
          #pragma unroll
          for (int mt = 0; mt < 4; ++mt) {
            acc1[mt][nt] = MFMA16(ahi[mt], bhi, acc1[mt][nt]);
            acc1[mt][nt] = MFMA16(alo[mt], bhi, acc1[mt][nt]);
            acc1[mt][nt] = MFMA16(ahi[mt], blo, acc1[mt][nt]);
          }
        }
      }
      #pragma unroll
      for (int mt = 0; mt < 4; ++mt)
        #pragma unroll
        for (int nt = 0; nt < 2; ++nt)
          #pragma unroll
          for (int r = 0; r < 4; ++r) {
            const float xg = acc1[mt][nt][r];
            const float z2 = 1.5957691216f * (xg + 0.044715f*xg*xg*xg); // 2*sqrt(2/pi)*(x+0.044715x^3)
            const float hres = xg - xg/(__expf(z2) + 1.f);              // tanh-gelu
            const int row = mt*16 + lh*4 + r;
            const int jb = (wid*32 + nt*16 + lc) << 1;
            const int adr = (row<<8) + (jb ^ ((row&7)<<4));
            const u16 hh = f2bfu(hres);
            *(u16*)(sm2 + HHI + adr) = hh;
            *(u16*)(sm2 + HLO + adr) = f2bfu(hres - bfu2f(hh));
          }
    }
    __syncthreads();   // h quarter visible to all waves

    { // GEMM2 partial: (64x128)@(128x128) split, accumulate
      #pragma unroll
      for (int kk = 0; kk < 4; ++kk) {
        bf16x8 ahi[4], alo[4];
        #pragma unroll
        for (int mt = 0; mt < 4; ++mt) {
          const int row = mt*16 + lc, cb = kk*64 + lh*16;
          const int adr = (row<<8) + (cb ^ ((row&7)<<4));
          ahi[mt] = ldb8(sm2 + HHI + adr);
          alo[mt] = ldb8(sm2 + HLO + adr);
        }
        #pragma unroll
        for (int nt = 0; nt < 2; ++nt) {
          const int c = wid*32 + nt*16 + lc;
          const bf16x8 bhi = ldb8(w2hi + c*512 + jq*128 + kk*32 + lh*8);
          const bf16x8 blo = ldb8(w2lo + c*512 + jq*128 + kk*32 + lh*8);
          #pragma unroll
          for (int mt = 0; mt < 4; ++mt) {
            acc2[mt][nt] = MFMA16(ahi[mt], bhi, acc2[mt][nt]);
            acc2[mt][nt] = MFMA16(alo[mt], bhi, acc2[mt][nt]);
            acc2[mt][nt] = MFMA16(ahi[mt], blo, acc2[mt][nt]);
          }
        }
      }
    }
    if (jq < 3) __syncthreads();   // before next quarter overwrites h buffers
  }

  #pragma unroll
  for (int mt = 0; mt < 4; ++mt)
    #pragma unroll
    for (int nt = 0; nt < 2; ++nt) {
      const int c = wid*32 + nt*16 + lc;
      #pragma unroll
      for (int r = 0; r < 4; ++r) {
        const int row = mt*16 + lh*4 + r;
        outp[((size_t)(tk0 + row) << 7) + c] = acc2[mt][nt][r];
      }
    }
}

extern "C" void kernel_launch(void* const* d_in, const int* in_sizes, int n_in,
                              void* d_out, int out_size, void* d_ws, size_t ws_size,
                              hipStream_t stream) {
  const float* emb  = (const float*)d_in[0];
  const float* ln1s = (const float*)d_in[1];
  const float* ln1b = (const float*)d_in[2];
  const float* wq   = (const float*)d_in[3];
  const float* bq   = (const float*)d_in[4];
  const float* wk   = (const float*)d_in[5];
  const float* bk   = (const float*)d_in[6];
  const float* wv   = (const float*)d_in[7];
  const float* bv   = (const float*)d_in[8];
  const float* bt   = (const float*)d_in[9];
  const float* wo   = (const float*)d_in[10];
  const float* bo   = (const float*)d_in[11];
  const float* wp   = (const float*)d_in[12];
  const float* bp   = (const float*)d_in[13];
  const float* ln2s = (const float*)d_in[14];
  const float* ln2b = (const float*)d_in[15];
  const float* w1   = (const float*)d_in[16];
  const float* b1   = (const float*)d_in[17];
  const float* w2   = (const float*)d_in[18];
  const float* b2   = (const float*)d_in[19];
  // rel_pos (d_in[20]) and attn_mask (d_in[21]) are recomputed analytically in k_prep.

  char* ws = (char*)d_ws;
  u16*   wqkvT  = (u16*)(ws + WS_WQKVT);
  u16*   woT    = (u16*)(ws + WS_WOT);
  u16*   wpT    = (u16*)(ws + WS_WPT);
  u16*   w1hi   = (u16*)(ws + WS_W1HI);
  u16*   w1lo   = (u16*)(ws + WS_W1LO);
  u16*   w2hi   = (u16*)(ws + WS_W2HI);
  u16*   w2lo   = (u16*)(ws + WS_W2LO);
  float* bqkv   = (float*)(ws + WS_BQKV);
  float* bm     = (float*)(ws + WS_BM);
  float* emb2   = (float*)d_out;   // LN2 input staged in d_out; overwritten by k_mlp

  k_prep<<<1090, 256, 0, stream>>>(wq, bq, wk, bk, wv, bv, bt, wo, wp, w1, w2,
                                   wqkvT, bqkv, woT, wpT, w1hi, w1lo, w2hi, w2lo, bm);
  k_attn<<<1568, 256, 0, stream>>>(emb, ln1s, ln1b, wqkvT, bqkv, bm,
                                   woT, bo, wpT, bp, emb2);
  k_mlp<<<1568, 256, 0, stream>>>(emb2, ln2s, ln2b, w1hi, w1lo, b1, w2hi, w2lo, b2,
                                  (float*)d_out);
}